// Round 11
// baseline (107.916 us; speedup 1.0000x reference)
//
#include <hip/hip_runtime.h>
#include <math.h>

#define EPS 1e-7f

constexpr int B = 16, L = 1024, D = 256, P = 20;
constexpr int LD = L * D;     // 262144
constexpr int DD = D * D;     // 65536

typedef __attribute__((ext_vector_type(8))) _Float16 f16x8;
typedef __attribute__((ext_vector_type(4))) float f32x4;

// ---------------------------------------------------------------------------
// ws layout (float slots):
//   tp   @0        131072   fp32 [32][B][D]   t partials
//   CT   @131072   2097152  fp16 [B][D][L]    s2*sqrt(invn2), transposed
//   Gf   @2228224  524288   fp16 [B][D][D]    gram (1048576 halves)
//   tsg  @2752512  4096     fp32 [B][D]       reduced t (after Gf)
// Round 11: mav latency trim.  (1) epilogue reuses the GEMM's af[] register
// fragments (same rowg -> identical As reads) instead of re-reading LDS;
// (2) GEMM j-loop software-pipelined with explicit bcur/bnxt register
// double-buffer (fully unrolled, static indexing) so next B-tile's L2 loads
// overlap current MFMAs; (3) k2h shrunk to 20 rows (p>=20 lanes clamp to
// row 0; outputs discarded at the p<P store guard).  prep2/gram unchanged.
// ---------------------------------------------------------------------------

#define MAV_SCALE 0.00390625f   // 1/256, exact in fp16

__device__ inline unsigned short f2h(float x) {
    _Float16 h = (_Float16)x;
    union { _Float16 h; unsigned short u; } c; c.h = h; return c.u;
}
__device__ inline float h2f(unsigned short u) {
    union { unsigned short u; _Float16 h; } c; c.u = u; return (float)c.h;
}

// K1: one pass over s2.  Block = 32 rows (b, m0..m0+31), 512 threads.
// (unchanged, verified)
__global__ __launch_bounds__(512) void k_prep2(const float* __restrict__ s2,
                                               float* __restrict__ tp,
                                               unsigned short* __restrict__ CT) {
    __shared__ float tile[32][260];
    __shared__ float wiv[32];
    __shared__ float wsq[32];
    __shared__ float tpp[2][256];
    int tid = threadIdx.x;
    int b   = blockIdx.x >> 5, mt = blockIdx.x & 31;
    int m0  = mt * 32;
    const float* gbase = s2 + (size_t)b * LD + (size_t)m0 * D;
    float4 v[4];
#pragma unroll
    for (int i = 0; i < 4; ++i) {
        int u = tid + i * 512;
        v[i] = *(const float4*)(gbase + (size_t)(u >> 6) * D + (u & 63) * 4);
    }
#pragma unroll
    for (int i = 0; i < 4; ++i) {
        int u = tid + i * 512;
        *(float4*)&tile[u >> 6][(u & 63) * 4] = v[i];
    }
    __syncthreads();
    {
        int r = tid >> 4, seg = tid & 15;
        float s = 0.f;
#pragma unroll
        for (int q = 0; q < 4; ++q) {
            float4 x = *(const float4*)&tile[r][seg * 16 + q * 4];
            s += x.x * x.x + x.y * x.y + x.z * x.z + x.w * x.w;
        }
#pragma unroll
        for (int o = 8; o; o >>= 1) s += __shfl_down(s, o, 16);
        if (seg == 0) {
            float iv = 1.0f / sqrtf(fmaxf(s, EPS));
            wiv[r] = iv;
            wsq[r] = sqrtf(iv);
        }
    }
    __syncthreads();
    {
        int dc = tid & 255, h = tid >> 8;
        float tpart = 0.f;
#pragma unroll
        for (int mm = 0; mm < 16; ++mm) {
            int m = h * 16 + mm;
            tpart += tile[m][dc] * wiv[m];
        }
        tpp[h][dc] = tpart;
    }
    {
        unsigned short* cbase = CT + (size_t)b * LD + m0;
#pragma unroll
        for (int i = 0; i < 2; ++i) {
            int u = tid + i * 512;
            int d = u >> 2, c = u & 3;
            union { unsigned short us[8]; uint4 q; } pk;
#pragma unroll
            for (int k = 0; k < 8; ++k) {
                int m = c * 8 + k;
                pk.us[k] = f2h(tile[m][d] * wsq[m]);
            }
            *(uint4*)(cbase + (size_t)d * L + c * 8) = pk.q;
        }
    }
    __syncthreads();
    if (tid < 256)
        tp[(size_t)(mt * B + b) * D + tid] = tpp[0][tid] + tpp[1][tid];
}

// K2: gram G = C C^T, SYMMETRIC ti<=tj tiles, LDS staging, K-split 4 waves.
// Grid 576.  t==0 block reduces tp -> tsg for its b.  (unchanged, verified)
__global__ __launch_bounds__(256) void k_gram32(const unsigned short* __restrict__ CT,
                                                const float* __restrict__ tp,
                                                unsigned short* __restrict__ Gf,
                                                float* __restrict__ tsg) {
    __shared__ short smem[2 * 32 * 264];
    short* As = smem;
    short* Bs = smem + 32 * 264;
    int tid = threadIdx.x;
    int b   = blockIdx.x / 36;
    int t   = blockIdx.x - b * 36;
    int ti = 0, rem = t;
    while (rem >= 8 - ti) { rem -= 8 - ti; ++ti; }
    int tj = ti + rem;
    bool diag = (ti == tj);
    int wave = tid >> 6, lane = tid & 63;
    int lr = lane & 15, lq = lane >> 4;

    const unsigned short* rowA = CT + (size_t)b * LD + (size_t)(ti * 32) * L;
    const unsigned short* rowB = CT + (size_t)b * LD + (size_t)(tj * 32) * L;

    f32x4 acc[2][2];
#pragma unroll
    for (int i = 0; i < 2; ++i)
#pragma unroll
        for (int j = 0; j < 2; ++j) acc[i][j] = (f32x4){0.f, 0.f, 0.f, 0.f};

#pragma unroll 1
    for (int kb = 0; kb < 4; ++kb) {
        int koff = kb * 256;
        __syncthreads();
        {
#pragma unroll
            for (int i = 0; i < 4; ++i) {
                int u = tid + i * 256;
                int row = u >> 5, c = u & 31;
                *(uint4*)&As[row * 264 + c * 8] =
                    *(const uint4*)(rowA + (size_t)row * L + koff + c * 8);
            }
            if (!diag) {
#pragma unroll
                for (int i = 0; i < 4; ++i) {
                    int u = tid + i * 256;
                    int row = u >> 5, c = u & 31;
                    *(uint4*)&Bs[row * 264 + c * 8] =
                        *(const uint4*)(rowB + (size_t)row * L + koff + c * 8);
                }
            }
        }
        __syncthreads();
        const short* Bp = diag ? As : Bs;
#pragma unroll
        for (int kk = 0; kk < 2; ++kk) {
            int ks = wave * 2 + kk;
            f16x8 af[2], bf[2];
#pragma unroll
            for (int i = 0; i < 2; ++i)
                af[i] = *(const f16x8*)&As[(i * 16 + lr) * 264 + ks * 32 + lq * 8];
#pragma unroll
            for (int j = 0; j < 2; ++j)
                bf[j] = *(const f16x8*)&Bp[(j * 16 + lr) * 264 + ks * 32 + lq * 8];
#pragma unroll
            for (int i = 0; i < 2; ++i)
#pragma unroll
                for (int j = 0; j < 2; ++j)
                    acc[i][j] = __builtin_amdgcn_mfma_f32_16x16x32_f16(af[i], bf[j], acc[i][j], 0, 0, 0);
        }
    }
    __syncthreads();
    float* red = (float*)smem;
#pragma unroll
    for (int i = 0; i < 2; ++i)
#pragma unroll
        for (int j = 0; j < 2; ++j)
#pragma unroll
            for (int r = 0; r < 4; ++r) {
                int row = i * 16 + lq * 4 + r, col = j * 16 + lr;
                red[wave * 1056 + row * 33 + col] = acc[i][j][r];
            }
    __syncthreads();
    unsigned short* gout = Gf + (size_t)b * DD;
#pragma unroll
    for (int k = 0; k < 4; ++k) {
        int e = tid + k * 256;
        int row = e >> 5, col = e & 31;
        float s = red[row * 33 + col] + red[1056 + row * 33 + col] +
                  red[2112 + row * 33 + col] + red[3168 + row * 33 + col];
        gout[(size_t)(ti * 32 + row) * D + tj * 32 + col] = f2h(s);
    }
    if (!diag) {
#pragma unroll
        for (int k = 0; k < 4; ++k) {
            int e = tid + k * 256;
            int r2 = e >> 5, c2 = e & 31;
            float s = red[c2 * 33 + r2] + red[1056 + c2 * 33 + r2] +
                      red[2112 + c2 * 33 + r2] + red[3168 + c2 * 33 + r2];
            gout[(size_t)(tj * 32 + r2) * D + ti * 32 + c2] = f2h(s);
        }
    }
    if (t == 0) {
        float a = 0.f;
#pragma unroll
        for (int mc = 0; mc < 32; ++mc) a += tp[(size_t)(mc * B + b) * D + tid];
        tsg[b * 256 + tid] = a;
    }
}

// K3: FUSED mav = s1 @ G + MFMA epilogue.
// Block = 32 l rows, 256 threads (4 waves), LDS ~45.5KB.  Grid 512.
// Round 11: af[] reused in epilogue; GEMM j-loop register double-buffered;
// k2h 20 rows (clamped reads for discarded p>=20 lanes).
__global__ __launch_bounds__(256) void k_mav_out(const float* __restrict__ s1,
                                                 const float* __restrict__ tsg,
                                                 const unsigned short* __restrict__ Gf,
                                                 const float* __restrict__ kern,
                                                 float* __restrict__ out) {
    __shared__ short As[32 * 264];
    __shared__ short Ms[32 * 264];
    __shared__ short k2h[P * 264];
    __shared__ float ts[256];
    __shared__ float sgnS[32];
    int tid  = threadIdx.x;
    int b    = blockIdx.x >> 5, lt = blockIdx.x & 31;
    int l0   = lt * 32;
    int wave = tid >> 6, lane = tid & 63;
    int lr   = lane & 15, lq = lane >> 4;

    // (0) issue s1 loads NOW; consumed after the staging barrier
    int r = tid >> 3, seg = tid & 7;
    const float* gp = s1 + (size_t)(b * L + l0 + r) * D + seg * 32;
    float4 v8[8];
#pragma unroll
    for (int q8 = 0; q8 < 8; ++q8) v8[q8] = ((const float4*)gp)[q8];

    // (a) ts load + k2h stage (20 rows only)
    ts[tid] = tsg[b * 256 + tid];
#pragma unroll
    for (int p = 0; p < P; ++p) {
        float v = kern[p * D + tid];
        k2h[p * 264 + tid] = f2h(v * v);
    }
    __syncthreads();

    // (b) s1 -> As fp16; per-row sign of (s1.t + EPS*n1).  8 thr/row.
    {
        float up = 0.f, sq = 0.f;
        union { unsigned short us[32]; uint4 q[4]; } hb;
#pragma unroll
        for (int q8 = 0; q8 < 8; ++q8) {
            float4 v = v8[q8];
            int td = seg * 32 + q8 * 4;
            up += v.x * ts[td] + v.y * ts[td + 1] + v.z * ts[td + 2] + v.w * ts[td + 3];
            sq += v.x * v.x + v.y * v.y + v.z * v.z + v.w * v.w;
            hb.us[q8 * 4 + 0] = f2h(v.x); hb.us[q8 * 4 + 1] = f2h(v.y);
            hb.us[q8 * 4 + 2] = f2h(v.z); hb.us[q8 * 4 + 3] = f2h(v.w);
        }
        short* la = &As[r * 264 + seg * 32];
        ((uint4*)la)[0] = hb.q[0]; ((uint4*)la)[1] = hb.q[1];
        ((uint4*)la)[2] = hb.q[2]; ((uint4*)la)[3] = hb.q[3];
#pragma unroll
        for (int o = 4; o; o >>= 1) { up += __shfl_down(up, o, 8); sq += __shfl_down(sq, o, 8); }
        if (seg == 0) {
            float n1v = sqrtf(fmaxf(sq, EPS));
            sgnS[r] = up + EPS * n1v;          // only the sign is ever used
        }
    }
    __syncthreads();

    int rowg = wave & 1;
    int c0   = (wave >> 1) * 128;

    // af fragments: loaded once, reused by GEMM AND epilogue (same rowg rows)
    f16x8 af[8];
#pragma unroll
    for (int ks = 0; ks < 8; ++ks)
        af[ks] = *(const f16x8*)&As[(rowg * 16 + lr) * 264 + ks * 32 + lq * 8];

    // (c) GEMM: register double-buffered over the 8 j-tiles
    {
        const unsigned short* gb0 = Gf + (size_t)b * DD + (size_t)(c0 + lr) * D + lq * 8;
        f16x8 bcur[8], bnxt[8];
#pragma unroll
        for (int ks = 0; ks < 8; ++ks)
            bcur[ks] = *(const f16x8*)(gb0 + ks * 32);
#pragma unroll
        for (int j = 0; j < 8; ++j) {
            if (j < 7) {
                const unsigned short* gbn = gb0 + (size_t)((j + 1) * 16) * D;
#pragma unroll
                for (int ks = 0; ks < 8; ++ks)
                    bnxt[ks] = *(const f16x8*)(gbn + ks * 32);
            }
            f32x4 acc = (f32x4){0.f, 0.f, 0.f, 0.f};
#pragma unroll
            for (int ks = 0; ks < 8; ++ks)
                acc = __builtin_amdgcn_mfma_f32_16x16x32_f16(af[ks], bcur[ks], acc, 0, 0, 0);
#pragma unroll
            for (int r4 = 0; r4 < 4; ++r4)
                Ms[(rowg * 16 + lq * 4 + r4) * 264 + c0 + j * 16 + lr] =
                    f2h(acc[r4] * MAV_SCALE);
#pragma unroll
            for (int ks = 0; ks < 8; ++ks) bcur[ks] = bnxt[ks];
        }
    }
    __syncthreads();

    // (d) MFMA epilogue: wave w -> rowg (af reused), pt = w>>1
    {
        int pt = wave >> 1;
        int p  = pt * 16 + lr;
        int pr = (p < P) ? p : 0;              // clamped row; result discarded
        f32x4 ax = (f32x4){0.f, 0.f, 0.f, 0.f};
        f32x4 an = (f32x4){0.f, 0.f, 0.f, 0.f};
        f32x4 am = (f32x4){0.f, 0.f, 0.f, 0.f};
#pragma unroll
        for (int ks = 0; ks < 8; ++ks) {
            f16x8 sa = af[ks];
            f16x8 ma = *(const f16x8*)&Ms[(rowg * 16 + lr) * 264 + ks * 32 + lq * 8];
            f16x8 bf = *(const f16x8*)&k2h[pr * 264 + ks * 32 + lq * 8];
            f16x8 xa = sa * ma;
            f16x8 s2 = sa * sa;
            f16x8 m2 = ma * ma;
            ax = __builtin_amdgcn_mfma_f32_16x16x32_f16(xa, bf, ax, 0, 0, 0);
            an = __builtin_amdgcn_mfma_f32_16x16x32_f16(s2, bf, an, 0, 0, 0);
            am = __builtin_amdgcn_mfma_f32_16x16x32_f16(m2, bf, am, 0, 0, 0);
        }
        if (p < P) {
#pragma unroll
            for (int r4 = 0; r4 < 4; ++r4) {
                int row = rowg * 16 + lq * 4 + r4;
                float sgn = (sgnS[row] < 0.f) ? -1.f : 1.f;
                out[(size_t)(b * L + l0 + row) * P + p] =
                    sgn * ax[r4] * rsqrtf(fmaxf(an[r4], EPS)) * rsqrtf(fmaxf(am[r4], EPS));
            }
        }
    }
}

extern "C" void kernel_launch(void* const* d_in, const int* in_sizes, int n_in,
                              void* d_out, int out_size, void* d_ws, size_t ws_size,
                              hipStream_t stream) {
    const float* s1   = (const float*)d_in[0];
    const float* s2   = (const float*)d_in[1];
    const float* kern = (const float*)d_in[2];
    float* out = (float*)d_out;
    float* ws  = (float*)d_ws;

    float* tp = ws;                                            // 131072 f
    unsigned short* CT = (unsigned short*)(ws + 131072);       // 4194304 h
    unsigned short* Gf = (unsigned short*)(ws + 2228224);      // 1048576 h -> ends @2752512 f
    float* tsg = ws + 2752512;                                 // 4096 f (after Gf)

    k_prep2<<<512, 512, 0, stream>>>(s2, tp, CT);
    k_gram32<<<576, 256, 0, stream>>>(CT, tp, Gf, tsg);
    k_mav_out<<<512, 256, 0, stream>>>(s1, tsg, Gf, kern, out);
}

// Round 12
// 107.399 us; speedup vs baseline: 1.0048x; 1.0048x over previous
//
#include <hip/hip_runtime.h>
#include <math.h>

#define EPS 1e-7f

constexpr int B = 16, L = 1024, D = 256, P = 20;
constexpr int LD = L * D;     // 262144
constexpr int DD = D * D;     // 65536

typedef __attribute__((ext_vector_type(8))) _Float16 f16x8;
typedef __attribute__((ext_vector_type(4))) float f32x4;

// ---------------------------------------------------------------------------
// ws layout (float slots):
//   tp   @0        131072   fp32 [32][B][D]   t partials
//   CT   @131072   2097152  fp16 [B][D][L]    s2*sqrt(invn2), transposed
//   Gf   @2228224  524288   fp16 [B][D][D]    gram (1048576 halves)
//   tsg  @2752512  4096     fp32 [B][D]       reduced t (after Gf)
// Round 12: occupancy doubling (round 11 lesson: mav/gram are latency-bound
// at 8-9 waves/CU, not traffic- or dependency-bound).
//   - gram: 512 thr / 8-wave K-split (16 MFMA/wave); red = 8x1056 f =
//     exactly the 33.8KB smem overlay.  16 waves/CU.
//   - mav: 512 thr / 8 waves; GEMM wave = (rowg, 64-col quarter), j-loop 4;
//     epilogue on waves 0-3 only.  2 blocks/CU x 8 = 16 waves/CU.
//   - prep2 unchanged (HBM-bound already).
// ---------------------------------------------------------------------------

#define MAV_SCALE 0.00390625f   // 1/256, exact in fp16

__device__ inline unsigned short f2h(float x) {
    _Float16 h = (_Float16)x;
    union { _Float16 h; unsigned short u; } c; c.h = h; return c.u;
}
__device__ inline float h2f(unsigned short u) {
    union { unsigned short u; _Float16 h; } c; c.u = u; return (float)c.h;
}

// K1: one pass over s2.  Block = 32 rows (b, m0..m0+31), 512 threads.
// (unchanged, verified)
__global__ __launch_bounds__(512) void k_prep2(const float* __restrict__ s2,
                                               float* __restrict__ tp,
                                               unsigned short* __restrict__ CT) {
    __shared__ float tile[32][260];
    __shared__ float wiv[32];
    __shared__ float wsq[32];
    __shared__ float tpp[2][256];
    int tid = threadIdx.x;
    int b   = blockIdx.x >> 5, mt = blockIdx.x & 31;
    int m0  = mt * 32;
    const float* gbase = s2 + (size_t)b * LD + (size_t)m0 * D;
    float4 v[4];
#pragma unroll
    for (int i = 0; i < 4; ++i) {
        int u = tid + i * 512;
        v[i] = *(const float4*)(gbase + (size_t)(u >> 6) * D + (u & 63) * 4);
    }
#pragma unroll
    for (int i = 0; i < 4; ++i) {
        int u = tid + i * 512;
        *(float4*)&tile[u >> 6][(u & 63) * 4] = v[i];
    }
    __syncthreads();
    {
        int r = tid >> 4, seg = tid & 15;
        float s = 0.f;
#pragma unroll
        for (int q = 0; q < 4; ++q) {
            float4 x = *(const float4*)&tile[r][seg * 16 + q * 4];
            s += x.x * x.x + x.y * x.y + x.z * x.z + x.w * x.w;
        }
#pragma unroll
        for (int o = 8; o; o >>= 1) s += __shfl_down(s, o, 16);
        if (seg == 0) {
            float iv = 1.0f / sqrtf(fmaxf(s, EPS));
            wiv[r] = iv;
            wsq[r] = sqrtf(iv);
        }
    }
    __syncthreads();
    {
        int dc = tid & 255, h = tid >> 8;
        float tpart = 0.f;
#pragma unroll
        for (int mm = 0; mm < 16; ++mm) {
            int m = h * 16 + mm;
            tpart += tile[m][dc] * wiv[m];
        }
        tpp[h][dc] = tpart;
    }
    {
        unsigned short* cbase = CT + (size_t)b * LD + m0;
#pragma unroll
        for (int i = 0; i < 2; ++i) {
            int u = tid + i * 512;
            int d = u >> 2, c = u & 3;
            union { unsigned short us[8]; uint4 q; } pk;
#pragma unroll
            for (int k = 0; k < 8; ++k) {
                int m = c * 8 + k;
                pk.us[k] = f2h(tile[m][d] * wsq[m]);
            }
            *(uint4*)(cbase + (size_t)d * L + c * 8) = pk.q;
        }
    }
    __syncthreads();
    if (tid < 256)
        tp[(size_t)(mt * B + b) * D + tid] = tpp[0][tid] + tpp[1][tid];
}

// K2: gram G = C C^T, SYMMETRIC ti<=tj tiles.  512 threads, 8-wave K-split
// (wave w owns k-slice w*32 of each staged 256-chunk).  Grid 576.
// t==0 block reduces tp -> tsg for its b.
__global__ __launch_bounds__(512) void k_gram32(const unsigned short* __restrict__ CT,
                                                const float* __restrict__ tp,
                                                unsigned short* __restrict__ Gf,
                                                float* __restrict__ tsg) {
    __shared__ short smem[2 * 32 * 264];   // As, Bs; red overlay = 8448 f exact
    short* As = smem;
    short* Bs = smem + 32 * 264;
    int tid = threadIdx.x;
    int b   = blockIdx.x / 36;
    int t   = blockIdx.x - b * 36;
    int ti = 0, rem = t;
    while (rem >= 8 - ti) { rem -= 8 - ti; ++ti; }
    int tj = ti + rem;
    bool diag = (ti == tj);
    int wave = tid >> 6, lane = tid & 63;
    int lr = lane & 15, lq = lane >> 4;

    const unsigned short* rowA = CT + (size_t)b * LD + (size_t)(ti * 32) * L;
    const unsigned short* rowB = CT + (size_t)b * LD + (size_t)(tj * 32) * L;

    f32x4 acc[2][2];
#pragma unroll
    for (int i = 0; i < 2; ++i)
#pragma unroll
        for (int j = 0; j < 2; ++j) acc[i][j] = (f32x4){0.f, 0.f, 0.f, 0.f};

#pragma unroll 1
    for (int kb = 0; kb < 4; ++kb) {
        int koff = kb * 256;
        __syncthreads();
        {
#pragma unroll
            for (int i = 0; i < 2; ++i) {
                int u = tid + i * 512;
                int row = u >> 5, c = u & 31;
                *(uint4*)&As[row * 264 + c * 8] =
                    *(const uint4*)(rowA + (size_t)row * L + koff + c * 8);
            }
            if (!diag) {
#pragma unroll
                for (int i = 0; i < 2; ++i) {
                    int u = tid + i * 512;
                    int row = u >> 5, c = u & 31;
                    *(uint4*)&Bs[row * 264 + c * 8] =
                        *(const uint4*)(rowB + (size_t)row * L + koff + c * 8);
                }
            }
        }
        __syncthreads();
        const short* Bp = diag ? As : Bs;
        {
            int ks = wave;                     // this wave's K slice (0..7)
            f16x8 af[2], bf[2];
#pragma unroll
            for (int i = 0; i < 2; ++i)
                af[i] = *(const f16x8*)&As[(i * 16 + lr) * 264 + ks * 32 + lq * 8];
#pragma unroll
            for (int j = 0; j < 2; ++j)
                bf[j] = *(const f16x8*)&Bp[(j * 16 + lr) * 264 + ks * 32 + lq * 8];
#pragma unroll
            for (int i = 0; i < 2; ++i)
#pragma unroll
                for (int j = 0; j < 2; ++j)
                    acc[i][j] = __builtin_amdgcn_mfma_f32_16x16x32_f16(af[i], bf[j], acc[i][j], 0, 0, 0);
        }
    }
    __syncthreads();                           // MFMA reads done -> reuse smem
    float* red = (float*)smem;                 // [8][32][33] = 8448 f exact
#pragma unroll
    for (int i = 0; i < 2; ++i)
#pragma unroll
        for (int j = 0; j < 2; ++j)
#pragma unroll
            for (int r = 0; r < 4; ++r) {
                int row = i * 16 + lq * 4 + r, col = j * 16 + lr;
                red[wave * 1056 + row * 33 + col] = acc[i][j][r];
            }
    __syncthreads();
    unsigned short* gout = Gf + (size_t)b * DD;
#pragma unroll
    for (int k = 0; k < 2; ++k) {
        int e = tid + k * 512;
        int row = e >> 5, col = e & 31;
        float s = 0.f;
#pragma unroll
        for (int w = 0; w < 8; ++w) s += red[w * 1056 + row * 33 + col];
        gout[(size_t)(ti * 32 + row) * D + tj * 32 + col] = f2h(s);
    }
    if (!diag) {
#pragma unroll
        for (int k = 0; k < 2; ++k) {
            int e = tid + k * 512;
            int r2 = e >> 5, c2 = e & 31;
            float s = 0.f;
#pragma unroll
            for (int w = 0; w < 8; ++w) s += red[w * 1056 + c2 * 33 + r2];
            gout[(size_t)(tj * 32 + r2) * D + ti * 32 + c2] = f2h(s);
        }
    }
    if (t == 0 && tid < 256) {
        float a = 0.f;
#pragma unroll
        for (int mc = 0; mc < 32; ++mc) a += tp[(size_t)(mc * B + b) * D + tid];
        tsg[b * 256 + tid] = a;
    }
}

// K3: FUSED mav = s1 @ G + MFMA epilogue.
// Block = 32 l rows, 512 threads (8 waves), LDS ~45.5KB -> 2 blocks/CU =
// 16 waves/CU.  Grid 512.  GEMM wave = (rowg=w&1, 64-col quarter w>>1),
// j-loop 4 tiles; epilogue on waves 0-3.
__global__ __launch_bounds__(512) void k_mav_out(const float* __restrict__ s1,
                                                 const float* __restrict__ tsg,
                                                 const unsigned short* __restrict__ Gf,
                                                 const float* __restrict__ kern,
                                                 float* __restrict__ out) {
    __shared__ short As[32 * 264];
    __shared__ short Ms[32 * 264];
    __shared__ short k2h[P * 264];
    __shared__ float ts[256];
    __shared__ float sgnS[32];
    int tid  = threadIdx.x;
    int b    = blockIdx.x >> 5, lt = blockIdx.x & 31;
    int l0   = lt * 32;
    int wave = tid >> 6, lane = tid & 63;
    int lr   = lane & 15, lq = lane >> 4;

    // (0) issue s1 loads NOW; 16 thr/row x 16 floats
    int r = tid >> 4, seg = tid & 15;
    const float* gp = s1 + (size_t)(b * L + l0 + r) * D + seg * 16;
    float4 v4[4];
#pragma unroll
    for (int q4 = 0; q4 < 4; ++q4) v4[q4] = ((const float4*)gp)[q4];

    // (a) ts load + k2h stage (20 rows, p-halves across 512 threads)
    if (tid < 256) ts[tid] = tsg[b * 256 + tid];
    {
        int d = tid & 255, ph = tid >> 8;
#pragma unroll
        for (int i = 0; i < 10; ++i) {
            int p = i * 2 + ph;
            float v = kern[p * D + d];
            k2h[p * 264 + d] = f2h(v * v);
        }
    }
    __syncthreads();

    // (b) s1 -> As fp16; per-row sign of (s1.t + EPS*n1).  16 thr/row.
    {
        float up = 0.f, sq = 0.f;
        union { unsigned short us[16]; uint4 q[2]; } hb;
#pragma unroll
        for (int q4 = 0; q4 < 4; ++q4) {
            float4 v = v4[q4];
            int td = seg * 16 + q4 * 4;
            up += v.x * ts[td] + v.y * ts[td + 1] + v.z * ts[td + 2] + v.w * ts[td + 3];
            sq += v.x * v.x + v.y * v.y + v.z * v.z + v.w * v.w;
            hb.us[q4 * 4 + 0] = f2h(v.x); hb.us[q4 * 4 + 1] = f2h(v.y);
            hb.us[q4 * 4 + 2] = f2h(v.z); hb.us[q4 * 4 + 3] = f2h(v.w);
        }
        short* la = &As[r * 264 + seg * 16];
        ((uint4*)la)[0] = hb.q[0]; ((uint4*)la)[1] = hb.q[1];
#pragma unroll
        for (int o = 8; o; o >>= 1) { up += __shfl_down(up, o, 16); sq += __shfl_down(sq, o, 16); }
        if (seg == 0) {
            float n1v = sqrtf(fmaxf(sq, EPS));
            sgnS[r] = up + EPS * n1v;          // only the sign is ever used
        }
    }
    __syncthreads();

    int rowg = wave & 1;

    // af fragments: loaded once, reused by GEMM and (waves 0-3) epilogue
    f16x8 af[8];
#pragma unroll
    for (int ks = 0; ks < 8; ++ks)
        af[ks] = *(const f16x8*)&As[(rowg * 16 + lr) * 264 + ks * 32 + lq * 8];

    // (c) GEMM: wave w -> rowg, cols c0 = (w>>1)*64, 4 j-tiles
    {
        int c0 = (wave >> 1) * 64;
        const unsigned short* gb0 = Gf + (size_t)b * DD + (size_t)(c0 + lr) * D + lq * 8;
#pragma unroll
        for (int j = 0; j < 4; ++j) {
            const unsigned short* gb = gb0 + (size_t)(j * 16) * D;
            f32x4 acc = (f32x4){0.f, 0.f, 0.f, 0.f};
#pragma unroll
            for (int ks = 0; ks < 8; ++ks) {
                f16x8 bf = *(const f16x8*)(gb + ks * 32);
                acc = __builtin_amdgcn_mfma_f32_16x16x32_f16(af[ks], bf, acc, 0, 0, 0);
            }
#pragma unroll
            for (int r4 = 0; r4 < 4; ++r4)
                Ms[(rowg * 16 + lq * 4 + r4) * 264 + c0 + j * 16 + lr] =
                    f2h(acc[r4] * MAV_SCALE);
        }
    }
    __syncthreads();

    // (d) MFMA epilogue: waves 0-3 (rowg = w&1, pt = w>>1 in {0,1})
    if (wave < 4) {
        int pt = wave >> 1;
        int p  = pt * 16 + lr;
        int pr = (p < P) ? p : 0;              // clamped row; result discarded
        f32x4 ax = (f32x4){0.f, 0.f, 0.f, 0.f};
        f32x4 an = (f32x4){0.f, 0.f, 0.f, 0.f};
        f32x4 am = (f32x4){0.f, 0.f, 0.f, 0.f};
#pragma unroll
        for (int ks = 0; ks < 8; ++ks) {
            f16x8 sa = af[ks];
            f16x8 ma = *(const f16x8*)&Ms[(rowg * 16 + lr) * 264 + ks * 32 + lq * 8];
            f16x8 bf = *(const f16x8*)&k2h[pr * 264 + ks * 32 + lq * 8];
            f16x8 xa = sa * ma;
            f16x8 s2 = sa * sa;
            f16x8 m2 = ma * ma;
            ax = __builtin_amdgcn_mfma_f32_16x16x32_f16(xa, bf, ax, 0, 0, 0);
            an = __builtin_amdgcn_mfma_f32_16x16x32_f16(s2, bf, an, 0, 0, 0);
            am = __builtin_amdgcn_mfma_f32_16x16x32_f16(m2, bf, am, 0, 0, 0);
        }
        if (p < P) {
#pragma unroll
            for (int r4 = 0; r4 < 4; ++r4) {
                int row = rowg * 16 + lq * 4 + r4;
                float sgn = (sgnS[row] < 0.f) ? -1.f : 1.f;
                out[(size_t)(b * L + l0 + row) * P + p] =
                    sgn * ax[r4] * rsqrtf(fmaxf(an[r4], EPS)) * rsqrtf(fmaxf(am[r4], EPS));
            }
        }
    }
}

extern "C" void kernel_launch(void* const* d_in, const int* in_sizes, int n_in,
                              void* d_out, int out_size, void* d_ws, size_t ws_size,
                              hipStream_t stream) {
    const float* s1   = (const float*)d_in[0];
    const float* s2   = (const float*)d_in[1];
    const float* kern = (const float*)d_in[2];
    float* out = (float*)d_out;
    float* ws  = (float*)d_ws;

    float* tp = ws;                                            // 131072 f
    unsigned short* CT = (unsigned short*)(ws + 131072);       // 4194304 h
    unsigned short* Gf = (unsigned short*)(ws + 2228224);      // 1048576 h -> ends @2752512 f
    float* tsg = ws + 2752512;                                 // 4096 f (after Gf)

    k_prep2<<<512, 512, 0, stream>>>(s2, tp, CT);
    k_gram32<<<576, 512, 0, stream>>>(CT, tp, Gf, tsg);
    k_mav_out<<<512, 512, 0, stream>>>(s1, tsg, Gf, kern, out);
}